// Round 10
// baseline (1208.915 us; speedup 1.0000x reference)
//
#include <hip/hip_runtime.h>
#include <hip/hip_bf16.h>
#include <stdint.h>
#include <stddef.h>

typedef __hip_bfloat16 bf16;
typedef __attribute__((ext_vector_type(8))) short bf8_t;   // 8 bf16 (4 VGPRs)
typedef __attribute__((ext_vector_type(4))) float f4_t;    // 4 f32 acc
static const int CH[5] = {16, 32, 64, 128, 256};

__device__ __forceinline__ float b2f(unsigned short u) {
    return __uint_as_float(((unsigned int)u) << 16);
}
__device__ __forceinline__ unsigned short f2bu(float f) {
    union { bf16 h; unsigned short u; } cv;
    cv.h = __float2bfloat16(f);
    return cv.u;
}
__device__ __forceinline__ void fma4(float4& a, float s, const float4& w) {
    a.x = fmaf(s, w.x, a.x);
    a.y = fmaf(s, w.y, a.y);
    a.z = fmaf(s, w.z, a.z);
    a.w = fmaf(s, w.w, a.w);
}
struct us4 { unsigned short a, b, c, d; };

// bijective chunked XCD swizzle (m204 form): phys block b runs on XCD b&7;
// give each XCD a CONTIGUOUS chunk of logical block ids so its gather
// window fits the private 4MB L2 (rulebook is spatially sorted).
__device__ __forceinline__ int xcd_swz(int b, int nb) {
    int q = nb >> 3, r = nb & 7;
    int x = b & 7, y = b >> 3;
    return (x < r) ? (x * (q + 1) + y) : (r * (q + 1) + (x - r) * q + y);
}

__global__ void k_sentinel(float* __restrict__ out, float v) {
    if (threadIdx.x == 0) out[0] = v;
}

// probe: flag[2]=1 if masks are int32-bools (vs byte-bools)
__global__ void SparseConvEncoder_20633022890309_kernel(
        const unsigned char* __restrict__ bM0, int* __restrict__ flag) {
    if (threadIdx.x == 0) {
        flag[0] = 1;
        flag[1] = 0;
        flag[2] = (bM0[0] == 1 && bM0[1] == 0 && bM0[2] == 0 && bM0[3] == 0 && bM0[4] == 1) ? 1 : 0;
    }
}

__global__ void __launch_bounds__(256) k_copy(const float* __restrict__ x,
                                              float* __restrict__ y, long n) {
    long i = (long)blockIdx.x * 256 + threadIdx.x;
    if (i < n) y[i] = x[i];
}

// copy f32 -> out and bf16 -> xb in one pass
__global__ void __launch_bounds__(256) k_copytob(const float* __restrict__ x,
                                                 float* __restrict__ y,
                                                 unsigned short* __restrict__ yb, long n) {
    long i = (long)blockIdx.x * 256 + threadIdx.x;
    if (i < n) {
        float v = x[i];
        y[i] = v;
        yb[i] = f2bu(v);
    }
}

// ---- weight repack ----
// Tiled (MFMA wave-linear) layout for cin>=32:
//   W2[kk][coTile][cb][lane l][8 bf16]; lane l=q*16+m holds W[kk][ci=cb*32+q*8+e][co=coTile*16+m].
// Old layout [kk][co][ci] retained for cin==16 (packed-offset path).
__device__ __forceinline__ long wt_tiled_src(long j, int cin, int cout) {
    int e = (int)(j & 7);
    int l = (int)((j >> 3) & 63);
    int m = l & 15, q = l >> 4;
    long u = j >> 9;
    int NC = cin >> 5;
    int cout16 = cout >> 4;
    int cb = (int)(u % NC); u /= NC;
    int ct = (int)(u % cout16);
    int kk = (int)(u / cout16);
    int ci = cb * 32 + q * 8 + e;
    int co = ct * 16 + m;
    return ((long)kk * cin + ci) * cout + co;
}

__global__ void __launch_bounds__(256) k_wt2(const float* __restrict__ dW,
                                             unsigned short* __restrict__ dWt, int dcin,
                                             const float* __restrict__ bW,
                                             unsigned short* __restrict__ bWt, int bcin,
                                             int cout, long dtot, long btot) {
    long i = (long)blockIdx.x * 256 + threadIdx.x;
    if (i < dtot) {
        if (dcin == 16) {
            long cc = (long)dcin * cout;
            int k = (int)(i / cc);
            int rem = (int)(i % cc);
            int co = rem / dcin, ci = rem % dcin;
            dWt[i] = f2bu(dW[((long)k * dcin + ci) * cout + co]);
        } else {
            dWt[i] = f2bu(dW[wt_tiled_src(i, dcin, cout)]);
        }
    } else if (i < dtot + btot) {
        long j = i - dtot;
        bWt[j] = f2bu(bW[wt_tiled_src(j, bcin, cout)]);
    }
}

// prefill R with the zero-row index zr AND zero the dummy row of the gather source.
__global__ void __launch_bounds__(256) k_prep(int* __restrict__ R, long cnt, int zr,
                                              unsigned short* __restrict__ zrow, int zc) {
    long i = (long)blockIdx.x * 256 + threadIdx.x;
    if (i < cnt) R[i] = zr;
    if (i < zc) zrow[i] = 0;
}

// dense rulebook chunk for offsets [k0,k0+g): R[(k-k0)*S + O] = I   (P = valid rows, S = row stride)
__global__ void __launch_bounds__(256) k_scatter(const int* __restrict__ I,
                                                 const int* __restrict__ O,
                                                 const void* __restrict__ M,
                                                 const int* __restrict__ flag,
                                                 int* __restrict__ R, int P, int S,
                                                 int k0, int cnt) {
    int i = blockIdx.x * 256 + threadIdx.x;
    if (i >= cnt) return;
    long gi = (long)k0 * P + i;
    int m = flag[2] ? ((const int*)M)[gi] : (int)((const unsigned char*)M)[gi];
    if (!m) return;
    R[(long)(i / P) * S + O[gi]] = I[gi];
}

__global__ void __launch_bounds__(256) k_init(float* __restrict__ out,
                                              const float* __restrict__ bias,
                                              long total, int maskC) {
    long i = (long)blockIdx.x * 256 + threadIdx.x;
    if (i < total) out[i] = bias ? bias[i & maskC] : 0.f;
}

// ======================= MFMA gather conv =======================
// Wave computes 16 rows x (16*TN) cout cols via mfma_f32_16x16x32_bf16.
// A from Xb row R[kk][o] (R prefilled with a zeroed dummy row -> pure loads).
// B from tiled Wt; KT path stages the first LKK offsets' B in LDS (52KB cap ->
// 3 blocks/CU). XCD-chunked blockIdx.x swizzle keeps each XCD's gather window
// in its private 4MB L2.
// MODE 0: init bias/0, store. MODE 1: init from out, store. MODE 2: zero, atomicAdd (K-split blockIdx.z).
// MODE0-KT epilogue optionally fuses BN partial stats (s1/s2 per channel via
// q-group shfl reduce + one atomicAdd pair per block) -> k_stats skipped.
template <int CIN, int TN, int MODE, int KT>
__global__ void __launch_bounds__(256, 2) k_mconv(const unsigned short* __restrict__ Xb,
                                                  const unsigned short* __restrict__ Wt,
                                                  const float* __restrict__ bias,
                                                  const int* __restrict__ R,
                                                  float* __restrict__ out,
                                                  float* __restrict__ bnsums,
                                                  int n, int cout, int kcnt, int gs) {
    const int lane = threadIdx.x & 63;
    const int wave = threadIdx.x >> 6;
    const int sbx = xcd_swz(blockIdx.x, gridDim.x);
    const int rt = sbx * 4 + wave;
    const int row_tiles = (n + 15) >> 4;
    const int n16 = row_tiles << 4;
    const int m = lane & 15, q = lane >> 4;
    const int o = rt * 16 + m;
    const int co0 = blockIdx.y * (16 * TN);
    const int bt = blockIdx.y * TN;             // cout16-tile base
    const int cout16 = cout >> 4;
    const bf8_t zero = {};

    constexpr int NCq = (CIN >= 32) ? (CIN / 32) : 1;
    // staged-offset count: cap LDS at 52KB so 3 blocks/CU fit
    constexpr int LKK_RAW = 52 / (TN * NCq);
    constexpr int LKK = (KT > 0 && CIN >= 32) ? ((LKK_RAW < KT) ? LKK_RAW : KT) : 0;
    constexpr bool LDSB = (LKK > 0);
    __shared__ short ldsb[LDSB ? (LKK * TN * NCq * 512) : 1];

    if constexpr (LDSB) {
        // cooperative stage of this block's B slice for kk<LKK: [kk][t][cb][lane][8]
        constexpr int CH16 = LKK * TN * NCq * 64;
        for (int i = threadIdx.x; i < CH16; i += 256) {
            int l = i & 63;
            int u = i >> 6;
            int cb = u % NCq; u /= NCq;
            int t = u % TN;
            int kk = u / TN;
            long gx = ((((long)kk * cout16 + bt + t) * NCq + cb) * 64 + l) * 8;
            *(bf8_t*)(ldsb + (size_t)i * 8) = *(const bf8_t*)(Wt + gx);
        }
        __syncthreads();
    }

    if (rt >= row_tiles) return;

    f4_t acc[TN];
#pragma unroll
    for (int t = 0; t < TN; ++t) {
        if (MODE == 0) {
            float bv = bias ? bias[co0 + t * 16 + m] : 0.f;
            acc[t][0] = bv; acc[t][1] = bv; acc[t][2] = bv; acc[t][3] = bv;
        } else if (MODE == 1) {
#pragma unroll
            for (int g = 0; g < 4; ++g) {
                int row = rt * 16 + q * 4 + g;
                acc[t][g] = (row < n) ? out[(long)row * cout + co0 + t * 16 + m] : 0.f;
            }
        } else {
            acc[t][0] = 0.f; acc[t][1] = 0.f; acc[t][2] = 0.f; acc[t][3] = 0.f;
        }
    }

    if constexpr (KT > 0) {
        // ---- fully-unrolled compile-time-K path (MODE 0), pure loads ----
        int r[KT];
#pragma unroll
        for (int kk = 0; kk < KT; ++kk)
            r[kk] = R[(long)kk * n16 + o];

        if constexpr (CIN == 16) {
            // pack offsets (2p, 2p+1) into one K=32 MFMA; prefetch ALL A first
            bf8_t a[KT / 2];
#pragma unroll
            for (int p = 0; p < KT / 2; ++p) {
                int rsel = (q < 2) ? r[2 * p] : r[2 * p + 1];
                a[p] = *(const bf8_t*)(Xb + (long)rsel * CIN + (q & 1) * 8);
            }
            __builtin_amdgcn_sched_barrier(0);
#pragma unroll
            for (int p = 0; p < KT / 2; ++p) {
                int ksel = 2 * p + (q >> 1);
#pragma unroll
                for (int t = 0; t < TN; ++t) {
                    int co = co0 + t * 16 + m;
                    long bxw = ((long)ksel * cout + co) * CIN + (q & 1) * 8;
                    bf8_t b = *(const bf8_t*)(Wt + bxw);
                    acc[t] = __builtin_amdgcn_mfma_f32_16x16x32_bf16(a[p], b, acc[t], 0, 0, 0);
                }
            }
        } else {
            constexpr int NC = CIN / 32;
            constexpr int GB = (KT * NC * 4 <= 128) ? KT : ((KT > 9) ? 9 : KT);
            constexpr int NG = (KT + GB - 1) / GB;

#define PRE_GRP(A, G0)                                                              \
    _Pragma("unroll")                                                               \
    for (int j = 0; j < GB; ++j) {                                                  \
        _Pragma("unroll")                                                           \
        for (int cb = 0; cb < NC; ++cb) {                                           \
            A[j][cb] = *(const bf8_t*)(Xb + (long)r[(G0) + j] * CIN + cb * 32 + q * 8); \
        }                                                                           \
    }

#define CMP_GRP(A, G0)                                                              \
    _Pragma("unroll")                                                               \
    for (int j = 0; j < GB; ++j) {                                                  \
        _Pragma("unroll")                                                           \
        for (int cb = 0; cb < NC; ++cb) {                                           \
            _Pragma("unroll")                                                       \
            for (int t = 0; t < TN; ++t) {                                          \
                bf8_t b;                                                            \
                if ((G0) + j < LKK) {                                               \
                    long lx = ((((long)((G0) + j) * TN + t) * NC + cb) * 64 + lane) * 8; \
                    b = *(const bf8_t*)(ldsb + lx);                                 \
                } else {                                                            \
                    long bxw = ((((long)((G0) + j) * cout16 + bt + t) * NC + cb) * 64 + lane) * 8; \
                    b = *(const bf8_t*)(Wt + bxw);                                  \
                }                                                                   \
                acc[t] = __builtin_amdgcn_mfma_f32_16x16x32_bf16(A[j][cb], b,       \
                                                                 acc[t], 0, 0, 0);  \
            }                                                                       \
        }                                                                           \
    }

            if constexpr (NG == 1) {
                bf8_t a0[GB][NC];
                PRE_GRP(a0, 0)
                __builtin_amdgcn_sched_barrier(0);
                CMP_GRP(a0, 0)
            } else {
                static_assert(NG == 3, "phase structure assumes 3 groups");
                bf8_t a0[GB][NC];
                bf8_t a1[GB][NC];
                bf8_t a2[GB][NC];
                PRE_GRP(a0, 0)
                PRE_GRP(a1, GB)
                __builtin_amdgcn_sched_barrier(0);
                CMP_GRP(a0, 0)
                __builtin_amdgcn_sched_barrier(0);
                PRE_GRP(a2, 2 * GB)
                __builtin_amdgcn_sched_barrier(0);
                CMP_GRP(a1, GB)
                __builtin_amdgcn_sched_barrier(0);
                CMP_GRP(a2, 2 * GB)
            }
#undef PRE_GRP
#undef CMP_GRP
        }
    } else {
        // ---- runtime-K path (chunked MODE0/1, K-split MODE2), batched pure loads ----
        int ks = 0, ke = kcnt;
        if (MODE == 2) {
            ks = blockIdx.z * gs;
            ke = ks + gs;
            if (ke > kcnt) ke = kcnt;
        }
        constexpr int NC = (CIN >= 32) ? (CIN / 32) : 1;
        constexpr int JB = (CIN >= 128) ? 2 : 4;
        for (int kb = ks; kb < ke; kb += JB) {
            int rj[JB];
#pragma unroll
            for (int j = 0; j < JB; ++j) {
                int kk = kb + j;
                int kc = (kk < ke) ? kk : (ke - 1);
                rj[j] = R[(long)kc * n16 + o];
            }
            bf8_t a[JB][NC];
#pragma unroll
            for (int j = 0; j < JB; ++j) {
#pragma unroll
                for (int cb = 0; cb < NC; ++cb) {
                    if (CIN == 16) {
                        a[j][cb] = (q < 2) ? *(const bf8_t*)(Xb + (long)rj[j] * CIN + q * 8)
                                           : zero;
                    } else {
                        a[j][cb] = *(const bf8_t*)(Xb + (long)rj[j] * CIN + cb * 32 + q * 8);
                    }
                }
            }
            __builtin_amdgcn_sched_barrier(0);
#pragma unroll
            for (int j = 0; j < JB; ++j) {
                int kk = kb + j;
                if (kk >= ke) break;
#pragma unroll
                for (int cb = 0; cb < NC; ++cb) {
#pragma unroll
                    for (int t = 0; t < TN; ++t) {
                        bf8_t b;
                        if (CIN == 16) {
                            int co = co0 + t * 16 + m;
                            b = (q < 2) ? *(const bf8_t*)(Wt + ((long)kk * cout + co) * CIN + q * 8)
                                        : zero;
                        } else {
                            long bxw = ((((long)kk * cout16 + bt + t) * NC + cb) * 64 + lane) * 8;
                            b = *(const bf8_t*)(Wt + bxw);
                        }
                        acc[t] = __builtin_amdgcn_mfma_f32_16x16x32_bf16(a[j][cb], b,
                                                                         acc[t], 0, 0, 0);
                    }
                }
            }
        }
    }

#pragma unroll
    for (int t = 0; t < TN; ++t) {
#pragma unroll
        for (int g = 0; g < 4; ++g) {
            int row = rt * 16 + q * 4 + g;
            if (row >= n) continue;
            float* p = out + (long)row * cout + co0 + t * 16 + m;
            if (MODE == 2) atomicAdd(p, acc[t][g]);
            else *p = acc[t][g];
        }
    }

    // fused BN partial stats (MODE0-KT only): s1/s2 per channel
    if (MODE == 0 && KT > 0 && bnsums != nullptr) {
#pragma unroll
        for (int t = 0; t < TN; ++t) {
            float s1 = 0.f, s2 = 0.f;
#pragma unroll
            for (int g = 0; g < 4; ++g) {
                int row = rt * 16 + q * 4 + g;
                if (row < n) {
                    float v = acc[t][g];
                    s1 += v;
                    s2 = fmaf(v, v, s2);
                }
            }
            s1 += __shfl_xor(s1, 16, 64);
            s2 += __shfl_xor(s2, 16, 64);
            s1 += __shfl_xor(s1, 32, 64);
            s2 += __shfl_xor(s2, 32, 64);
            if (q == 0) {
                atomicAdd(&bnsums[co0 + t * 16 + m], s1);
                atomicAdd(&bnsums[cout + co0 + t * 16 + m], s2);
            }
        }
    }
}

static bool mconv_dispatch(int cin, int tn, int mode, int kt, dim3 grd,
                           const unsigned short* Xb, const unsigned short* Wt,
                           const float* bias, const int* R, float* out,
                           float* bnsums, int n, int cout, int kcnt, int gs,
                           hipStream_t stream) {
#define MF_(CC, TT, KK)                                                            \
    if (cin == CC && tn == TT && mode == 0 && kt == KK) {                          \
        k_mconv<CC, TT, 0, KK><<<grd, 256, 0, stream>>>(Xb, Wt, bias, R, out,      \
                                                        bnsums, n, cout, kcnt, gs);\
        return true;                                                               \
    }
    MF_(16, 2, 8) MF_(32, 2, 8) MF_(32, 4, 8) MF_(64, 2, 8) MF_(64, 4, 8)
    MF_(32, 2, 27) MF_(64, 2, 27) MF_(64, 4, 27)
#undef MF_
#define M3_(CC, TT, MM)                                                            \
    if (cin == CC && tn == TT && mode == MM) {                                     \
        k_mconv<CC, TT, MM, 0><<<grd, 256, 0, stream>>>(Xb, Wt, bias, R, out,      \
                                                        nullptr, n, cout, kcnt, gs);\
        return false;                                                              \
    }
#define M2_(CC) M3_(CC, 2, 0) M3_(CC, 2, 1) M3_(CC, 2, 2) \
                M3_(CC, 4, 0) M3_(CC, 4, 1) M3_(CC, 4, 2)
    M2_(16) M2_(32) M2_(64) M2_(128) M2_(256)
#undef M2_
#undef M3_
    return false;
}

// Xb: gather source with nin valid rows; row nin is the dummy zero row (zeroed by k_prep).
// Returns true if BN stats were fused into the conv epilogue (sums filled).
static bool run_mconv(unsigned short* Xb, int nin, const unsigned short* Wt,
                      const float* bias, const int* I, const int* O, const void* M,
                      const int* flag, int* R, float* out, int n, int cin, int cout,
                      int K, int G, float* sums, hipStream_t stream) {
    int rt = (n + 15) / 16;
    int n16 = rt * 16;
    int bx = (rt + 3) / 4;
    int tn = (cout >= 64) ? 4 : 2;
    int gy = cout / (16 * tn);
    long bxy = (long)bx * gy;
    int kg = 1;
    // STRICT < : bxy==512 grids (L1 convs) take the KT-MODE0 path — the full
    // pure-load + LDS-B + swizzle machinery beats MODE2's k_init + kg x atomic
    // writes (r6 lesson) at equal grid size.
    if (bxy < 512 && G >= K) {
        kg = (int)((1024 + bxy - 1) / bxy);
        if (kg > K) kg = K;
    }
    int gs = (K + kg - 1) / kg;
    kg = (K + gs - 1) / gs;
    unsigned short* zrow = Xb + (size_t)nin * cin;
    bool fused = false;

    if (kg > 1) {
        long cnt = (long)K * n16;
        k_prep<<<(int)((cnt + 255) / 256), 256, 0, stream>>>(R, cnt, nin, zrow, cin);
        k_scatter<<<(K * n + 255) / 256, 256, 0, stream>>>(I, O, M, flag, R, n, n16,
                                                           0, K * n);
        long tot = (long)n * cout;
        k_init<<<(int)((tot + 255) / 256), 256, 0, stream>>>(out, bias, tot, cout - 1);
        mconv_dispatch(cin, tn, 2, 0, dim3(bx, gy, kg), Xb, Wt, bias, R, out,
                       nullptr, n, cout, K, gs, stream);
    } else {
        for (int k0 = 0; k0 < K; k0 += G) {
            int g = (K - k0 < G) ? (K - k0) : G;
            long cnt = (long)g * n16;
            k_prep<<<(int)((cnt + 255) / 256), 256, 0, stream>>>(R, cnt, nin, zrow, cin);
            k_scatter<<<(g * n + 255) / 256, 256, 0, stream>>>(I, O, M, flag, R, n, n16,
                                                               k0, g * n);
            int kt = (k0 == 0 && g == K) ? K : 0;
            bool f = mconv_dispatch(cin, tn, (k0 == 0) ? 0 : 1, kt, dim3(bx, gy, 1), Xb,
                                    Wt + (size_t)k0 * cout * cin, bias, R, out,
                                    (kt > 0) ? sums : nullptr, n, cout, g, g, stream);
            fused = fused || f;
        }
    }
    return fused;
}

// ======================= fallback VALU conv (round-8 path) =======================
template <int CIN, int ROWS, int XBF, int MODE>
__global__ void __launch_bounds__(256) k_conv_t(const void* __restrict__ X,
                                                const float* __restrict__ W,
                                                const float* __restrict__ bias,
                                                const int* __restrict__ R,
                                                float* __restrict__ out,
                                                int n, int cout,
                                                int wk0, int kcnt, int gs) {
    const int c4 = threadIdx.x;
    const int by = blockDim.y;
    const int base = blockIdx.x * by * ROWS;
    const float* Xf = (const float*)X;
    const unsigned short* Xb = (const unsigned short*)X;

    int o[ROWS];
    float4 acc[ROWS];
    bool touched[ROWS];
#pragma unroll
    for (int j = 0; j < ROWS; ++j) {
        o[j] = base + j * by + threadIdx.y;
        touched[j] = false;
        acc[j] = make_float4(0.f, 0.f, 0.f, 0.f);
        if (o[j] < n) {
            if (MODE == 0) {
                if (bias) acc[j] = *(const float4*)(bias + c4 * 4);
            } else if (MODE == 1) {
                acc[j] = *(const float4*)(out + (long)o[j] * cout + c4 * 4);
            }
        }
    }
    int ks = 0, ke = kcnt;
    if (MODE == 2) {
        ks = blockIdx.y * gs;
        ke = ks + gs;
        if (ke > kcnt) ke = kcnt;
    }
    for (int kk = ks; kk < ke; ++kk) {
        int r[ROWS];
        bool any = false;
#pragma unroll
        for (int j = 0; j < ROWS; ++j) {
            r[j] = (o[j] < n) ? R[(long)kk * n + o[j]] : -1;
            any = any || (r[j] >= 0);
            touched[j] = touched[j] || (r[j] >= 0);
        }
        if (!any) continue;
        const float* wk = W + ((long)(wk0 + kk) * CIN) * cout + c4 * 4;
#pragma unroll
        for (int ci = 0; ci < CIN; ci += 4) {
            float4 w0 = *(const float4*)(wk + (long)(ci + 0) * cout);
            float4 w1 = *(const float4*)(wk + (long)(ci + 1) * cout);
            float4 w2 = *(const float4*)(wk + (long)(ci + 2) * cout);
            float4 w3 = *(const float4*)(wk + (long)(ci + 3) * cout);
#pragma unroll
            for (int j = 0; j < ROWS; ++j) {
                if (r[j] < 0) continue;
                float x0, x1, x2, x3;
                if (XBF) {
                    us4 u = *(const us4*)(Xb + (long)r[j] * CIN + ci);
                    x0 = b2f(u.a); x1 = b2f(u.b); x2 = b2f(u.c); x3 = b2f(u.d);
                } else {
                    float4 xv = *(const float4*)(Xf + (long)r[j] * CIN + ci);
                    x0 = xv.x; x1 = xv.y; x2 = xv.z; x3 = xv.w;
                }
                fma4(acc[j], x0, w0);
                fma4(acc[j], x1, w1);
                fma4(acc[j], x2, w2);
                fma4(acc[j], x3, w3);
            }
        }
    }
#pragma unroll
    for (int j = 0; j < ROWS; ++j) {
        if (o[j] >= n) continue;
        if (MODE == 2) {
            if (!touched[j]) continue;
            float* p = out + (long)o[j] * cout + c4 * 4;
            atomicAdd(p + 0, acc[j].x);
            atomicAdd(p + 1, acc[j].y);
            atomicAdd(p + 2, acc[j].z);
            atomicAdd(p + 3, acc[j].w);
        } else {
            *(float4*)(out + (long)o[j] * cout + c4 * 4) = acc[j];
        }
    }
}

static void conv_dispatch(int cin, int rows, int xbf, int mode, dim3 grd, dim3 blk,
                          const void* X, const float* W, const float* bias,
                          const int* R, float* out, int n, int cout,
                          int wk0, int kcnt, int gs, hipStream_t stream) {
#define C3_(CC, RR, XB, MM)                                                        \
    if (cin == CC && rows == RR && xbf == XB && mode == MM) {                      \
        k_conv_t<CC, RR, XB, MM><<<grd, blk, 0, stream>>>(X, W, bias, R, out, n,   \
                                                          cout, wk0, kcnt, gs);    \
        return;                                                                    \
    }
#define C2_(CC, RR) C3_(CC, RR, 0, 0) C3_(CC, RR, 0, 1) C3_(CC, RR, 0, 2) \
                    C3_(CC, RR, 1, 0) C3_(CC, RR, 1, 1) C3_(CC, RR, 1, 2)
#define C1_(CC) C2_(CC, 1) C2_(CC, 2) C2_(CC, 4)
    C1_(16) C1_(32) C1_(64) C1_(128) C1_(256)
#undef C1_
#undef C2_
#undef C3_
}

static void run_conv(const void* X, int xbf, const float* W, const float* bias,
                     const int* I, const int* O, const void* M, const int* flag,
                     int* R, float* out, int n, int cin, int cout, int K,
                     int G, hipStream_t stream) {
    int bx = cout / 4, by = 256 / bx;
    int g4 = (n + by * 4 - 1) / (by * 4);
    int g2 = (n + by * 2 - 1) / (by * 2);
    int rows;
    if (g4 >= 1024) rows = 4;
    else if (g2 >= 1024) rows = 2;
    else rows = 1;
    int gridn = (n + by * rows - 1) / (by * rows);
    int kg = 1;
    if (gridn < 768 && G >= K) {
        kg = (2048 + gridn - 1) / gridn;
        if (kg > K) kg = K;
    }
    int gs = (K + kg - 1) / kg;
    kg = (K + gs - 1) / gs;
    dim3 blk(bx, by);
    if (kg > 1) {
        int cnt = K * n;
        hipMemsetAsync(R, 0xFF, (size_t)cnt * 4, stream);
        k_scatter<<<(cnt + 255) / 256, 256, 0, stream>>>(I, O, M, flag, R, n, n, 0, cnt);
        long tot = (long)n * cout;
        k_init<<<(int)((tot + 255) / 256), 256, 0, stream>>>(out, bias, tot, cout - 1);
        conv_dispatch(cin, rows, xbf, 2, dim3(gridn, kg), blk, X, W, bias, R, out,
                      n, cout, 0, K, gs, stream);
    } else {
        for (int k0 = 0; k0 < K; k0 += G) {
            int g = (K - k0 < G) ? (K - k0) : G;
            int cnt = g * n;
            hipMemsetAsync(R, 0xFF, (size_t)cnt * 4, stream);
            k_scatter<<<(cnt + 255) / 256, 256, 0, stream>>>(I, O, M, flag, R, n, n, k0, cnt);
            conv_dispatch(cin, rows, xbf, (k0 == 0) ? 0 : 1, dim3(gridn, 1), blk,
                          X, W, bias, R, out, n, cout, k0, g, g, stream);
        }
    }
}

// ======================= BN =======================
__global__ void __launch_bounds__(256) k_stats(const float* __restrict__ X,
                                               float* __restrict__ sums, int n, int C) {
    int c = threadIdx.x, ty = threadIdx.y, ny = blockDim.y;
    float s1 = 0.f, s2 = 0.f;
    for (int o = blockIdx.x * ny + ty; o < n; o += gridDim.x * ny) {
        float v = X[(long)o * C + c];
        s1 += v;
        s2 += v * v;
    }
    __shared__ float sm[512];
    sm[ty * C + c] = s1;
    sm[256 + ty * C + c] = s2;
    __syncthreads();
    if (ty == 0) {
        for (int t = 1; t < ny; ++t) {
            s1 += sm[t * C + c];
            s2 += sm[256 + t * C + c];
        }
        atomicAdd(&sums[c], s1);
        atomicAdd(&sums[C + c], s2);
    }
}

__global__ void __launch_bounds__(256) k_apply(const float* __restrict__ X,
                                               const float* __restrict__ sums,
                                               const float* __restrict__ g,
                                               const float* __restrict__ b,
                                               void* __restrict__ Y, int ybf,
                                               unsigned short* __restrict__ Y2,
                                               long total, int maskC, int C, float inv_n) {
    long i = (long)blockIdx.x * 256 + threadIdx.x;
    if (i >= total) return;
    int c = (int)(i & (long)maskC);
    float mean = sums[c] * inv_n;
    float var = fmaf(-mean, mean, sums[C + c] * inv_n);
    float sc = g[c] * rsqrtf(var + 1e-5f);
    float sh = fmaf(-mean, sc, b[c]);
    float v = fmaf(X[i], sc, sh);
    v = v > 0.f ? v : 0.f;
    if (ybf) ((unsigned short*)Y)[i] = f2bu(v);
    else     ((float*)Y)[i] = v;
    if (Y2) Y2[i] = f2bu(v);
}

// sums must be zeroed BEFORE the producing conv (launcher does it);
// skip_stats=true when the conv epilogue already filled sums.
static void run_bn(const float* src, int n, int C, const float* g, const float* b,
                   void* dst, int dst_bf16, unsigned short* dst2,
                   float* sums, bool skip_stats, hipStream_t stream) {
    if (!skip_stats) {
        dim3 sblk(C, 256 / C);
        int sgrd = (n + (int)sblk.y - 1) / (int)sblk.y;
        if (sgrd > 1024) sgrd = 1024;
        k_stats<<<sgrd, sblk, 0, stream>>>(src, sums, n, C);
    }
    long tot = (long)n * C;
    k_apply<<<(int)((tot + 255) / 256), 256, 0, stream>>>(src, sums, g, b, dst, dst_bf16,
                                                          dst2, tot, C - 1, C,
                                                          1.0f / (float)n);
}

extern "C" void kernel_launch(void* const* d_in, const int* in_sizes, int n_in,
                              void* d_out, int out_size, void* d_ws, size_t ws_size,
                              hipStream_t stream) {
    float* out = (float*)d_out;

    int stride = 0;
    if (n_in == 57) stride = 14;
    else if (n_in == 53) stride = 13;
    if (!stride) {
        k_sentinel<<<1, 64, 0, stream>>>(out, 10240.f + (float)n_in);
        return;
    }
    static const int o14[13] = {0, 1, 2, 3, 4, 5, 7, 8, 9, 10, 11, 12, 13};
    static const int o13[13] = {0, 1, 2, 3, 4, 5, 6, 7, 8, 9, 10, 11, 12};
    const int* om = (stride == 14) ? o14 : o13;

    long n0 = (long)in_sizes[0];
    int P[4];
    bool ok = (n0 % 16 == 0);
    long total = n0;
    for (int l = 0; l < 4 && ok; ++l) {
        int base = 1 + stride * l;
        int sdI = in_sizes[base + om[1]], sdO = in_sizes[base + om[2]], sdM = in_sizes[base + om[3]];
        int sbI = in_sizes[base + om[8]], sbO = in_sizes[base + om[9]], sbM = in_sizes[base + om[10]];
        if (sdI <= 0 || sdI % 8 != 0 || sdO != sdI || sdM != sdI) { ok = false; break; }
        int p = sdI / 8;
        if (sbI != 27 * p || sbO != sbI || sbM != sbI) { ok = false; break; }
        if (in_sizes[base + om[0]] != 8 * CH[l] * CH[l + 1]) { ok = false; break; }
        if (in_sizes[base + om[6]] != 27 * CH[l + 1] * CH[l + 1]) { ok = false; break; }
        P[l] = p;
        total += (long)p * CH[l + 1];
    }
    if (!ok) {
        k_sentinel<<<1, 64, 0, stream>>>(out, 49152.f);
        return;
    }
    if (total != (long)out_size) {
        k_sentinel<<<1, 64, 0, stream>>>(out, 53248.f);
        return;
    }

    auto al = [](size_t x) { return (x + 255) / 256 * 256; };
    size_t maxBuf = 0, maxP = 0, maxXb = 0;
    long rowsIn[4] = {n0 / 16, P[0], P[1], P[2]};
    for (int l = 0; l < 4; ++l) {
        size_t b = (size_t)P[l] * CH[l + 1];
        if (b > maxBuf) maxBuf = b;
        if ((size_t)P[l] > maxP) maxP = (size_t)P[l];
        size_t xi = (size_t)rowsIn[l] * CH[l];
        if (xi > maxXb) maxXb = xi;
    }
    const size_t fixed = 4096;
    size_t rmin = al((maxP + 16) * 4);
    size_t dwt_sz = al((size_t)8 * 128 * 256 * 2);
    size_t bwt_sz = al((size_t)27 * 256 * 256 * 2);
    size_t xb_sz = al(maxXb * 2 + 1024);
    size_t bufB_sz = al(maxBuf * 2 + 1024);
    size_t mf_need = dwt_sz + bwt_sz + xb_sz + bufB_sz + fixed + rmin;

    if (ws_size >= mf_need) {
        // ---------------- MFMA bf16 path ----------------
        char* wsp = (char*)d_ws;
        unsigned short* dWt = (unsigned short*)wsp; wsp += dwt_sz;
        unsigned short* bWt = (unsigned short*)wsp; wsp += bwt_sz;
        unsigned short* xb = (unsigned short*)wsp;  wsp += xb_sz;
        unsigned short* bufB = (unsigned short*)wsp; wsp += bufB_sz;
        // r10 FIX: sums needs 2*256 floats = 2048B (cout=256 at level 3).
        // It was 1024B -> level-3 BN memset/k_stats overflowed into flag[],
        // zeroing flag[2] before L3-down's k_scatter (mask misread -> output 4
        // corrupt). r1-r8 only survived because the overflow happened AFTER
        // the scatter and left flag[2] truthy.
        float* sums = (float*)wsp; wsp += 2048;
        int* flag = (int*)wsp;     wsp += 2048;
        int* R = (int*)wsp;
        size_t Rbytes = ws_size - (size_t)(wsp - (char*)d_ws);

        SparseConvEncoder_20633022890309_kernel<<<1, 64, 0, stream>>>(
            (const unsigned char*)d_in[1 + om[10]], flag);
        k_copytob<<<(int)((n0 + 255) / 256), 256, 0, stream>>>((const float*)d_in[0],
                                                               out, xb, n0);

        long coff = n0;
        for (int l = 0; l < 4; ++l) {
            int base = 1 + stride * l;
            const float* dW = (const float*)d_in[base + om[0]];
            const int* dI = (const int*)d_in[base + om[1]];
            const int* dO = (const int*)d_in[base + om[2]];
            const void* dM = d_in[base + om[3]];
            const float* dG = (const float*)d_in[base + om[4]];
            const float* dB = (const float*)d_in[base + om[5]];
            const float* bW = (const float*)d_in[base + om[6]];
            const float* bC = (const float*)d_in[base + om[7]];
            const int* bI = (const int*)d_in[base + om[8]];
            const int* bO = (const int*)d_in[base + om[9]];
            const void* bM = d_in[base + om[10]];
            const float* bG = (const float*)d_in[base + om[11]];
            const float* bH = (const float*)d_in[base + om[12]];
            int n = P[l], cin = CH[l], cout = CH[l + 1];
            int nin = (int)rowsIn[l];
            int n16 = (n + 15) / 16 * 16;

            int G = (int)(Rbytes / ((size_t)n16 * 4));
            if (G > 27) G = 27;
            if (G < 1) G = 1;

            float* chunkp = out + coff;

            long dwtot = (long)8 * cin * cout;
            long bwtot = (long)27 * cout * cout;
            k_wt2<<<(int)((dwtot + bwtot + 255) / 256), 256, 0, stream>>>(
                dW, dWt, cin, bW, bWt, cout, cout, dwtot, bwtot);

            hipMemsetAsync(sums, 0, 2 * cout * sizeof(float), stream);
            bool f1 = run_mconv(xb, nin, dWt, nullptr, dI, dO, dM, flag, R, chunkp,
                                n, cin, cout, 8, (G > 8) ? 8 : G, sums, stream);
            run_bn(chunkp, n, cout, dG, dB, bufB, /*ybf=*/1, nullptr, sums, f1, stream);

            hipMemsetAsync(sums, 0, 2 * cout * sizeof(float), stream);
            bool f2 = run_mconv(bufB, n, bWt, bC, bI, bO, bM, flag, R, chunkp,
                                n, cout, cout, 27, G, sums, stream);
            run_bn(chunkp, n, cout, bG, bH, chunkp, /*ybf=*/0,
                   (l < 3) ? xb : nullptr, sums, f2, stream);

            coff += (long)n * cout;
        }
        return;
    }

    // ---------------- fallback VALU path ----------------
    int bufB_bf16;
    size_t bufBytes;
    if (ws_size >= fixed + al(maxBuf * 4) + rmin) { bufB_bf16 = 0; bufBytes = al(maxBuf * 4); }
    else if (ws_size >= fixed + al(maxBuf * 2) + rmin) { bufB_bf16 = 1; bufBytes = al(maxBuf * 2); }
    else {
        k_sentinel<<<1, 64, 0, stream>>>(out, 16384.f + (float)(ws_size >> 20));
        return;
    }
    size_t Rbytes = ws_size - fixed - bufBytes;
    char* wsp = (char*)d_ws;
    void* bufB = (void*)wsp;   wsp += bufBytes;
    float* sums = (float*)wsp; wsp += 2048;   // r10 FIX: 512 floats (cout=256)
    int* flag = (int*)wsp;     wsp += 2048;
    int* R = (int*)wsp;

    SparseConvEncoder_20633022890309_kernel<<<1, 64, 0, stream>>>(
        (const unsigned char*)d_in[1 + om[10]], flag);
    k_copy<<<(int)((n0 + 255) / 256), 256, 0, stream>>>((const float*)d_in[0], out, n0);

    long coff = n0;
    const void* cur_in = d_in[0];
    int cur_xbf = 0;
    for (int l = 0; l < 4; ++l) {
        int base = 1 + stride * l;
        const float* dW = (const float*)d_in[base + om[0]];
        const int* dI = (const int*)d_in[base + om[1]];
        const int* dO = (const int*)d_in[base + om[2]];
        const void* dM = d_in[base + om[3]];
        const float* dG = (const float*)d_in[base + om[4]];
        const float* dB = (const float*)d_in[base + om[5]];
        const float* bW = (const float*)d_in[base + om[6]];
        const float* bC = (const float*)d_in[base + om[7]];
        const int* bI = (const int*)d_in[base + om[8]];
        const int* bO = (const int*)d_in[base + om[9]];
        const void* bM = d_in[base + om[10]];
        const float* bG = (const float*)d_in[base + om[11]];
        const float* bH = (const float*)d_in[base + om[12]];
        int n = P[l], cin = CH[l], cout = CH[l + 1];

        int G = (int)(Rbytes / ((size_t)n * 4));
        if (G > 27) G = 27;
        if (G < 1) G = 1;

        float* chunkp = out + coff;
        run_conv(cur_in, cur_xbf, dW, nullptr, dI, dO, dM, flag, R, chunkp,
                 n, cin, cout, 8, (G > 8) ? 8 : G, stream);
        hipMemsetAsync(sums, 0, 2 * cout * sizeof(float), stream);
        run_bn(chunkp, n, cout, dG, dB, bufB, bufB_bf16, nullptr, sums, false, stream);
        run_conv(bufB, bufB_bf16, bW, bC, bI, bO, bM, flag, R, chunkp,
                 n, cout, cout, 27, G, stream);
        hipMemsetAsync(sums, 0, 2 * cout * sizeof(float), stream);
        run_bn(chunkp, n, cout, bG, bH, chunkp, /*ybf=*/0, nullptr, sums, false, stream);

        cur_in = (const void*)chunkp;
        cur_xbf = 0;
        coff += (long)n * cout;
    }
}

// Round 11
// 743.019 us; speedup vs baseline: 1.6270x; 1.6270x over previous
//
#include <hip/hip_runtime.h>
#include <hip/hip_bf16.h>
#include <stdint.h>
#include <stddef.h>

typedef __hip_bfloat16 bf16;
typedef __attribute__((ext_vector_type(8))) short bf8_t;   // 8 bf16 (4 VGPRs)
typedef __attribute__((ext_vector_type(4))) float f4_t;    // 4 f32 acc
static const int CH[5] = {16, 32, 64, 128, 256};

__device__ __forceinline__ float b2f(unsigned short u) {
    return __uint_as_float(((unsigned int)u) << 16);
}
__device__ __forceinline__ unsigned short f2bu(float f) {
    union { bf16 h; unsigned short u; } cv;
    cv.h = __float2bfloat16(f);
    return cv.u;
}
__device__ __forceinline__ void fma4(float4& a, float s, const float4& w) {
    a.x = fmaf(s, w.x, a.x);
    a.y = fmaf(s, w.y, a.y);
    a.z = fmaf(s, w.z, a.z);
    a.w = fmaf(s, w.w, a.w);
}
struct us4 { unsigned short a, b, c, d; };

// bijective chunked XCD swizzle: phys block b runs on XCD b&7; give each XCD a
// CONTIGUOUS chunk of logical block ids so its gather window fits the private 4MB L2.
__device__ __forceinline__ int xcd_swz(int b, int nb) {
    int q = nb >> 3, r = nb & 7;
    int x = b & 7, y = b >> 3;
    return (x < r) ? (x * (q + 1) + y) : (r * (q + 1) + (x - r) * q + y);
}

__global__ void k_sentinel(float* __restrict__ out, float v) {
    if (threadIdx.x == 0) out[0] = v;
}

// probe: flag[2]=1 if masks are int32-bools (vs byte-bools)
__global__ void SparseConvEncoder_20633022890309_kernel(
        const unsigned char* __restrict__ bM0, int* __restrict__ flag) {
    if (threadIdx.x == 0) {
        flag[0] = 1;
        flag[1] = 0;
        flag[2] = (bM0[0] == 1 && bM0[1] == 0 && bM0[2] == 0 && bM0[3] == 0 && bM0[4] == 1) ? 1 : 0;
    }
}

__global__ void __launch_bounds__(256) k_copy(const float* __restrict__ x,
                                              float* __restrict__ y, long n) {
    long i = (long)blockIdx.x * 256 + threadIdx.x;
    if (i < n) y[i] = x[i];
}

// copy f32 -> out and bf16 -> xb in one pass
__global__ void __launch_bounds__(256) k_copytob(const float* __restrict__ x,
                                                 float* __restrict__ y,
                                                 unsigned short* __restrict__ yb, long n) {
    long i = (long)blockIdx.x * 256 + threadIdx.x;
    if (i < n) {
        float v = x[i];
        y[i] = v;
        yb[i] = f2bu(v);
    }
}

// ---- weight repack ----
// Tiled (MFMA wave-linear) layout for cin>=32:
//   W2[kk][coTile][cb][lane l][8 bf16]; lane l=q*16+m holds W[kk][ci=cb*32+q*8+e][co=coTile*16+m].
// Old layout [kk][co][ci] retained for cin==16 (packed-offset path).
__device__ __forceinline__ long wt_tiled_src(long j, int cin, int cout) {
    int e = (int)(j & 7);
    int l = (int)((j >> 3) & 63);
    int m = l & 15, q = l >> 4;
    long u = j >> 9;
    int NC = cin >> 5;
    int cout16 = cout >> 4;
    int cb = (int)(u % NC); u /= NC;
    int ct = (int)(u % cout16);
    int kk = (int)(u / cout16);
    int ci = cb * 32 + q * 8 + e;
    int co = ct * 16 + m;
    return ((long)kk * cin + ci) * cout + co;
}

__global__ void __launch_bounds__(256) k_wt2(const float* __restrict__ dW,
                                             unsigned short* __restrict__ dWt, int dcin,
                                             const float* __restrict__ bW,
                                             unsigned short* __restrict__ bWt, int bcin,
                                             int cout, long dtot, long btot) {
    long i = (long)blockIdx.x * 256 + threadIdx.x;
    if (i < dtot) {
        if (dcin == 16) {
            long cc = (long)dcin * cout;
            int k = (int)(i / cc);
            int rem = (int)(i % cc);
            int co = rem / dcin, ci = rem % dcin;
            dWt[i] = f2bu(dW[((long)k * dcin + ci) * cout + co]);
        } else {
            dWt[i] = f2bu(dW[wt_tiled_src(i, dcin, cout)]);
        }
    } else if (i < dtot + btot) {
        long j = i - dtot;
        bWt[j] = f2bu(bW[wt_tiled_src(j, bcin, cout)]);
    }
}

// prefill R with the zero-row index zr AND zero the dummy row of the gather source.
__global__ void __launch_bounds__(256) k_prep(int* __restrict__ R, long cnt, int zr,
                                              unsigned short* __restrict__ zrow, int zc) {
    long i = (long)blockIdx.x * 256 + threadIdx.x;
    if (i < cnt) R[i] = zr;
    if (i < zc) zrow[i] = 0;
}

// dense rulebook chunk for offsets [k0,k0+g): R[(k-k0)*S + O] = I   (P = valid rows, S = row stride)
__global__ void __launch_bounds__(256) k_scatter(const int* __restrict__ I,
                                                 const int* __restrict__ O,
                                                 const void* __restrict__ M,
                                                 const int* __restrict__ flag,
                                                 int* __restrict__ R, int P, int S,
                                                 int k0, int cnt) {
    int i = blockIdx.x * 256 + threadIdx.x;
    if (i >= cnt) return;
    long gi = (long)k0 * P + i;
    int m = flag[2] ? ((const int*)M)[gi] : (int)((const unsigned char*)M)[gi];
    if (!m) return;
    R[(long)(i / P) * S + O[gi]] = I[gi];
}

__global__ void __launch_bounds__(256) k_init(float* __restrict__ out,
                                              const float* __restrict__ bias,
                                              long total, int maskC) {
    long i = (long)blockIdx.x * 256 + threadIdx.x;
    if (i < total) out[i] = bias ? bias[i & maskC] : 0.f;
}

// ======================= MFMA gather conv =======================
// Wave computes 16 rows x (16*TN) cout cols via mfma_f32_16x16x32_bf16.
// A from Xb row R[kk][o] (R prefilled with a zeroed dummy row -> pure loads).
// B from tiled Wt; KT path stages the first LKK offsets' B in LDS (52KB cap ->
// 3 blocks/CU). XCD-chunked blockIdx.x swizzle keeps each XCD's gather window
// in its private 4MB L2.
// MODE 0: init bias/0, store. MODE 1: init from out, store. MODE 2: zero, atomicAdd (K-split blockIdx.z).
// r10 lesson (REVERTED fused-BN): per-channel atomicAdd from every wave of a
// 2688-block grid = ~10k serialized same-address atomics per channel -> 43->270us.
// k_stats' 21.5MB re-read costs only ~6us. Never fuse grid-wide per-channel
// reductions via direct atomics.
template <int CIN, int TN, int MODE, int KT>
__global__ void __launch_bounds__(256, 2) k_mconv(const unsigned short* __restrict__ Xb,
                                                  const unsigned short* __restrict__ Wt,
                                                  const float* __restrict__ bias,
                                                  const int* __restrict__ R,
                                                  float* __restrict__ out,
                                                  int n, int cout, int kcnt, int gs) {
    const int lane = threadIdx.x & 63;
    const int wave = threadIdx.x >> 6;
    const int sbx = xcd_swz(blockIdx.x, gridDim.x);
    const int rt = sbx * 4 + wave;
    const int row_tiles = (n + 15) >> 4;
    const int n16 = row_tiles << 4;
    const int m = lane & 15, q = lane >> 4;
    const int o = rt * 16 + m;
    const int co0 = blockIdx.y * (16 * TN);
    const int bt = blockIdx.y * TN;             // cout16-tile base
    const int cout16 = cout >> 4;
    const bf8_t zero = {};

    constexpr int NCq = (CIN >= 32) ? (CIN / 32) : 1;
    // staged-offset count: cap LDS at 52KB so 3 blocks/CU fit
    constexpr int LKK_RAW = 52 / (TN * NCq);
    constexpr int LKK = (KT > 0 && CIN >= 32) ? ((LKK_RAW < KT) ? LKK_RAW : KT) : 0;
    constexpr bool LDSB = (LKK > 0);
    __shared__ short ldsb[LDSB ? (LKK * TN * NCq * 512) : 1];

    if constexpr (LDSB) {
        // cooperative stage of this block's B slice for kk<LKK: [kk][t][cb][lane][8]
        constexpr int CH16 = LKK * TN * NCq * 64;
        for (int i = threadIdx.x; i < CH16; i += 256) {
            int l = i & 63;
            int u = i >> 6;
            int cb = u % NCq; u /= NCq;
            int t = u % TN;
            int kk = u / TN;
            long gx = ((((long)kk * cout16 + bt + t) * NCq + cb) * 64 + l) * 8;
            *(bf8_t*)(ldsb + (size_t)i * 8) = *(const bf8_t*)(Wt + gx);
        }
        __syncthreads();
    }

    if (rt >= row_tiles) return;

    f4_t acc[TN];
#pragma unroll
    for (int t = 0; t < TN; ++t) {
        if (MODE == 0) {
            float bv = bias ? bias[co0 + t * 16 + m] : 0.f;
            acc[t][0] = bv; acc[t][1] = bv; acc[t][2] = bv; acc[t][3] = bv;
        } else if (MODE == 1) {
#pragma unroll
            for (int g = 0; g < 4; ++g) {
                int row = rt * 16 + q * 4 + g;
                acc[t][g] = (row < n) ? out[(long)row * cout + co0 + t * 16 + m] : 0.f;
            }
        } else {
            acc[t][0] = 0.f; acc[t][1] = 0.f; acc[t][2] = 0.f; acc[t][3] = 0.f;
        }
    }

    if constexpr (KT > 0) {
        // ---- fully-unrolled compile-time-K path (MODE 0), pure loads ----
        int r[KT];
#pragma unroll
        for (int kk = 0; kk < KT; ++kk)
            r[kk] = R[(long)kk * n16 + o];

        if constexpr (CIN == 16) {
            // pack offsets (2p, 2p+1) into one K=32 MFMA; prefetch ALL A first
            bf8_t a[KT / 2];
#pragma unroll
            for (int p = 0; p < KT / 2; ++p) {
                int rsel = (q < 2) ? r[2 * p] : r[2 * p + 1];
                a[p] = *(const bf8_t*)(Xb + (long)rsel * CIN + (q & 1) * 8);
            }
            __builtin_amdgcn_sched_barrier(0);
#pragma unroll
            for (int p = 0; p < KT / 2; ++p) {
                int ksel = 2 * p + (q >> 1);
#pragma unroll
                for (int t = 0; t < TN; ++t) {
                    int co = co0 + t * 16 + m;
                    long bxw = ((long)ksel * cout + co) * CIN + (q & 1) * 8;
                    bf8_t b = *(const bf8_t*)(Wt + bxw);
                    acc[t] = __builtin_amdgcn_mfma_f32_16x16x32_bf16(a[p], b, acc[t], 0, 0, 0);
                }
            }
        } else {
            constexpr int NC = CIN / 32;
            constexpr int GB = (KT * NC * 4 <= 128) ? KT : ((KT > 9) ? 9 : KT);
            constexpr int NG = (KT + GB - 1) / GB;

#define PRE_GRP(A, G0)                                                              \
    _Pragma("unroll")                                                               \
    for (int j = 0; j < GB; ++j) {                                                  \
        _Pragma("unroll")                                                           \
        for (int cb = 0; cb < NC; ++cb) {                                           \
            A[j][cb] = *(const bf8_t*)(Xb + (long)r[(G0) + j] * CIN + cb * 32 + q * 8); \
        }                                                                           \
    }

#define CMP_GRP(A, G0)                                                              \
    _Pragma("unroll")                                                               \
    for (int j = 0; j < GB; ++j) {                                                  \
        _Pragma("unroll")                                                           \
        for (int cb = 0; cb < NC; ++cb) {                                           \
            _Pragma("unroll")                                                       \
            for (int t = 0; t < TN; ++t) {                                          \
                bf8_t b;                                                            \
                if ((G0) + j < LKK) {                                               \
                    long lx = ((((long)((G0) + j) * TN + t) * NC + cb) * 64 + lane) * 8; \
                    b = *(const bf8_t*)(ldsb + lx);                                 \
                } else {                                                            \
                    long bxw = ((((long)((G0) + j) * cout16 + bt + t) * NC + cb) * 64 + lane) * 8; \
                    b = *(const bf8_t*)(Wt + bxw);                                  \
                }                                                                   \
                acc[t] = __builtin_amdgcn_mfma_f32_16x16x32_bf16(A[j][cb], b,       \
                                                                 acc[t], 0, 0, 0);  \
            }                                                                       \
        }                                                                           \
    }

            if constexpr (NG == 1) {
                bf8_t a0[GB][NC];
                PRE_GRP(a0, 0)
                __builtin_amdgcn_sched_barrier(0);
                CMP_GRP(a0, 0)
            } else {
                static_assert(NG == 3, "phase structure assumes 3 groups");
                bf8_t a0[GB][NC];
                bf8_t a1[GB][NC];
                bf8_t a2[GB][NC];
                PRE_GRP(a0, 0)
                PRE_GRP(a1, GB)
                __builtin_amdgcn_sched_barrier(0);
                CMP_GRP(a0, 0)
                __builtin_amdgcn_sched_barrier(0);
                PRE_GRP(a2, 2 * GB)
                __builtin_amdgcn_sched_barrier(0);
                CMP_GRP(a1, GB)
                __builtin_amdgcn_sched_barrier(0);
                CMP_GRP(a2, 2 * GB)
            }
#undef PRE_GRP
#undef CMP_GRP
        }
    } else {
        // ---- runtime-K path (chunked MODE0/1, K-split MODE2), batched pure loads ----
        int ks = 0, ke = kcnt;
        if (MODE == 2) {
            ks = blockIdx.z * gs;
            ke = ks + gs;
            if (ke > kcnt) ke = kcnt;
        }
        constexpr int NC = (CIN >= 32) ? (CIN / 32) : 1;
        constexpr int JB = (CIN >= 128) ? 2 : 4;
        for (int kb = ks; kb < ke; kb += JB) {
            int rj[JB];
#pragma unroll
            for (int j = 0; j < JB; ++j) {
                int kk = kb + j;
                int kc = (kk < ke) ? kk : (ke - 1);
                rj[j] = R[(long)kc * n16 + o];
            }
            bf8_t a[JB][NC];
#pragma unroll
            for (int j = 0; j < JB; ++j) {
#pragma unroll
                for (int cb = 0; cb < NC; ++cb) {
                    if (CIN == 16) {
                        a[j][cb] = (q < 2) ? *(const bf8_t*)(Xb + (long)rj[j] * CIN + q * 8)
                                           : zero;
                    } else {
                        a[j][cb] = *(const bf8_t*)(Xb + (long)rj[j] * CIN + cb * 32 + q * 8);
                    }
                }
            }
            __builtin_amdgcn_sched_barrier(0);
#pragma unroll
            for (int j = 0; j < JB; ++j) {
                int kk = kb + j;
                if (kk >= ke) break;
#pragma unroll
                for (int cb = 0; cb < NC; ++cb) {
#pragma unroll
                    for (int t = 0; t < TN; ++t) {
                        bf8_t b;
                        if (CIN == 16) {
                            int co = co0 + t * 16 + m;
                            b = (q < 2) ? *(const bf8_t*)(Wt + ((long)kk * cout + co) * CIN + q * 8)
                                        : zero;
                        } else {
                            long bxw = ((((long)kk * cout16 + bt + t) * NC + cb) * 64 + lane) * 8;
                            b = *(const bf8_t*)(Wt + bxw);
                        }
                        acc[t] = __builtin_amdgcn_mfma_f32_16x16x32_bf16(a[j][cb], b,
                                                                         acc[t], 0, 0, 0);
                    }
                }
            }
        }
    }

#pragma unroll
    for (int t = 0; t < TN; ++t) {
#pragma unroll
        for (int g = 0; g < 4; ++g) {
            int row = rt * 16 + q * 4 + g;
            if (row >= n) continue;
            float* p = out + (long)row * cout + co0 + t * 16 + m;
            if (MODE == 2) atomicAdd(p, acc[t][g]);
            else *p = acc[t][g];
        }
    }
}

static void mconv_dispatch(int cin, int tn, int mode, int kt, dim3 grd,
                           const unsigned short* Xb, const unsigned short* Wt,
                           const float* bias, const int* R, float* out,
                           int n, int cout, int kcnt, int gs, hipStream_t stream) {
#define MF_(CC, TT, KK)                                                            \
    if (cin == CC && tn == TT && mode == 0 && kt == KK) {                          \
        k_mconv<CC, TT, 0, KK><<<grd, 256, 0, stream>>>(Xb, Wt, bias, R, out, n,   \
                                                        cout, kcnt, gs);           \
        return;                                                                    \
    }
    MF_(16, 2, 8) MF_(32, 2, 8) MF_(32, 4, 8) MF_(64, 2, 8) MF_(64, 4, 8)
    MF_(32, 2, 27) MF_(64, 2, 27) MF_(64, 4, 27)
#undef MF_
#define M3_(CC, TT, MM)                                                            \
    if (cin == CC && tn == TT && mode == MM) {                                     \
        k_mconv<CC, TT, MM, 0><<<grd, 256, 0, stream>>>(Xb, Wt, bias, R, out, n,   \
                                                        cout, kcnt, gs);           \
        return;                                                                    \
    }
#define M2_(CC) M3_(CC, 2, 0) M3_(CC, 2, 1) M3_(CC, 2, 2) \
                M3_(CC, 4, 0) M3_(CC, 4, 1) M3_(CC, 4, 2)
    M2_(16) M2_(32) M2_(64) M2_(128) M2_(256)
#undef M2_
#undef M3_
}

// Xb: gather source with nin valid rows; row nin is the dummy zero row (zeroed by k_prep).
static void run_mconv(unsigned short* Xb, int nin, const unsigned short* Wt,
                      const float* bias, const int* I, const int* O, const void* M,
                      const int* flag, int* R, float* out, int n, int cin, int cout,
                      int K, int G, hipStream_t stream) {
    int rt = (n + 15) / 16;
    int n16 = rt * 16;
    int bx = (rt + 3) / 4;
    int tn = (cout >= 64) ? 4 : 2;
    int gy = cout / (16 * tn);
    long bxy = (long)bx * gy;
    int kg = 1;
    // STRICT < : bxy==512 grids (L1 convs) take the KT-MODE0 path — pure-load +
    // LDS-B + swizzle beats MODE2's k_init + kg x atomic writes (r6 lesson).
    if (bxy < 512 && G >= K) {
        kg = (int)((1024 + bxy - 1) / bxy);
        if (kg > K) kg = K;
    }
    int gs = (K + kg - 1) / kg;
    kg = (K + gs - 1) / gs;
    unsigned short* zrow = Xb + (size_t)nin * cin;

    if (kg > 1) {
        long cnt = (long)K * n16;
        k_prep<<<(int)((cnt + 255) / 256), 256, 0, stream>>>(R, cnt, nin, zrow, cin);
        k_scatter<<<(K * n + 255) / 256, 256, 0, stream>>>(I, O, M, flag, R, n, n16,
                                                           0, K * n);
        long tot = (long)n * cout;
        k_init<<<(int)((tot + 255) / 256), 256, 0, stream>>>(out, bias, tot, cout - 1);
        mconv_dispatch(cin, tn, 2, 0, dim3(bx, gy, kg), Xb, Wt, bias, R, out,
                       n, cout, K, gs, stream);
    } else {
        for (int k0 = 0; k0 < K; k0 += G) {
            int g = (K - k0 < G) ? (K - k0) : G;
            long cnt = (long)g * n16;
            k_prep<<<(int)((cnt + 255) / 256), 256, 0, stream>>>(R, cnt, nin, zrow, cin);
            k_scatter<<<(g * n + 255) / 256, 256, 0, stream>>>(I, O, M, flag, R, n, n16,
                                                               k0, g * n);
            int kt = (k0 == 0 && g == K) ? K : 0;
            mconv_dispatch(cin, tn, (k0 == 0) ? 0 : 1, kt, dim3(bx, gy, 1), Xb,
                           Wt + (size_t)k0 * cout * cin, bias, R, out,
                           n, cout, g, g, stream);
        }
    }
}

// ======================= fallback VALU conv (round-8 path) =======================
template <int CIN, int ROWS, int XBF, int MODE>
__global__ void __launch_bounds__(256) k_conv_t(const void* __restrict__ X,
                                                const float* __restrict__ W,
                                                const float* __restrict__ bias,
                                                const int* __restrict__ R,
                                                float* __restrict__ out,
                                                int n, int cout,
                                                int wk0, int kcnt, int gs) {
    const int c4 = threadIdx.x;
    const int by = blockDim.y;
    const int base = blockIdx.x * by * ROWS;
    const float* Xf = (const float*)X;
    const unsigned short* Xb = (const unsigned short*)X;

    int o[ROWS];
    float4 acc[ROWS];
    bool touched[ROWS];
#pragma unroll
    for (int j = 0; j < ROWS; ++j) {
        o[j] = base + j * by + threadIdx.y;
        touched[j] = false;
        acc[j] = make_float4(0.f, 0.f, 0.f, 0.f);
        if (o[j] < n) {
            if (MODE == 0) {
                if (bias) acc[j] = *(const float4*)(bias + c4 * 4);
            } else if (MODE == 1) {
                acc[j] = *(const float4*)(out + (long)o[j] * cout + c4 * 4);
            }
        }
    }
    int ks = 0, ke = kcnt;
    if (MODE == 2) {
        ks = blockIdx.y * gs;
        ke = ks + gs;
        if (ke > kcnt) ke = kcnt;
    }
    for (int kk = ks; kk < ke; ++kk) {
        int r[ROWS];
        bool any = false;
#pragma unroll
        for (int j = 0; j < ROWS; ++j) {
            r[j] = (o[j] < n) ? R[(long)kk * n + o[j]] : -1;
            any = any || (r[j] >= 0);
            touched[j] = touched[j] || (r[j] >= 0);
        }
        if (!any) continue;
        const float* wk = W + ((long)(wk0 + kk) * CIN) * cout + c4 * 4;
#pragma unroll
        for (int ci = 0; ci < CIN; ci += 4) {
            float4 w0 = *(const float4*)(wk + (long)(ci + 0) * cout);
            float4 w1 = *(const float4*)(wk + (long)(ci + 1) * cout);
            float4 w2 = *(const float4*)(wk + (long)(ci + 2) * cout);
            float4 w3 = *(const float4*)(wk + (long)(ci + 3) * cout);
#pragma unroll
            for (int j = 0; j < ROWS; ++j) {
                if (r[j] < 0) continue;
                float x0, x1, x2, x3;
                if (XBF) {
                    us4 u = *(const us4*)(Xb + (long)r[j] * CIN + ci);
                    x0 = b2f(u.a); x1 = b2f(u.b); x2 = b2f(u.c); x3 = b2f(u.d);
                } else {
                    float4 xv = *(const float4*)(Xf + (long)r[j] * CIN + ci);
                    x0 = xv.x; x1 = xv.y; x2 = xv.z; x3 = xv.w;
                }
                fma4(acc[j], x0, w0);
                fma4(acc[j], x1, w1);
                fma4(acc[j], x2, w2);
                fma4(acc[j], x3, w3);
            }
        }
    }
#pragma unroll
    for (int j = 0; j < ROWS; ++j) {
        if (o[j] >= n) continue;
        if (MODE == 2) {
            if (!touched[j]) continue;
            float* p = out + (long)o[j] * cout + c4 * 4;
            atomicAdd(p + 0, acc[j].x);
            atomicAdd(p + 1, acc[j].y);
            atomicAdd(p + 2, acc[j].z);
            atomicAdd(p + 3, acc[j].w);
        } else {
            *(float4*)(out + (long)o[j] * cout + c4 * 4) = acc[j];
        }
    }
}

static void conv_dispatch(int cin, int rows, int xbf, int mode, dim3 grd, dim3 blk,
                          const void* X, const float* W, const float* bias,
                          const int* R, float* out, int n, int cout,
                          int wk0, int kcnt, int gs, hipStream_t stream) {
#define C3_(CC, RR, XB, MM)                                                        \
    if (cin == CC && rows == RR && xbf == XB && mode == MM) {                      \
        k_conv_t<CC, RR, XB, MM><<<grd, blk, 0, stream>>>(X, W, bias, R, out, n,   \
                                                          cout, wk0, kcnt, gs);    \
        return;                                                                    \
    }
#define C2_(CC, RR) C3_(CC, RR, 0, 0) C3_(CC, RR, 0, 1) C3_(CC, RR, 0, 2) \
                    C3_(CC, RR, 1, 0) C3_(CC, RR, 1, 1) C3_(CC, RR, 1, 2)
#define C1_(CC) C2_(CC, 1) C2_(CC, 2) C2_(CC, 4)
    C1_(16) C1_(32) C1_(64) C1_(128) C1_(256)
#undef C1_
#undef C2_
#undef C3_
}

static void run_conv(const void* X, int xbf, const float* W, const float* bias,
                     const int* I, const int* O, const void* M, const int* flag,
                     int* R, float* out, int n, int cin, int cout, int K,
                     int G, hipStream_t stream) {
    int bx = cout / 4, by = 256 / bx;
    int g4 = (n + by * 4 - 1) / (by * 4);
    int g2 = (n + by * 2 - 1) / (by * 2);
    int rows;
    if (g4 >= 1024) rows = 4;
    else if (g2 >= 1024) rows = 2;
    else rows = 1;
    int gridn = (n + by * rows - 1) / (by * rows);
    int kg = 1;
    if (gridn < 768 && G >= K) {
        kg = (2048 + gridn - 1) / gridn;
        if (kg > K) kg = K;
    }
    int gs = (K + kg - 1) / kg;
    kg = (K + gs - 1) / gs;
    dim3 blk(bx, by);
    if (kg > 1) {
        int cnt = K * n;
        hipMemsetAsync(R, 0xFF, (size_t)cnt * 4, stream);
        k_scatter<<<(cnt + 255) / 256, 256, 0, stream>>>(I, O, M, flag, R, n, n, 0, cnt);
        long tot = (long)n * cout;
        k_init<<<(int)((tot + 255) / 256), 256, 0, stream>>>(out, bias, tot, cout - 1);
        conv_dispatch(cin, rows, xbf, 2, dim3(gridn, kg), blk, X, W, bias, R, out,
                      n, cout, 0, K, gs, stream);
    } else {
        for (int k0 = 0; k0 < K; k0 += G) {
            int g = (K - k0 < G) ? (K - k0) : G;
            int cnt = g * n;
            hipMemsetAsync(R, 0xFF, (size_t)cnt * 4, stream);
            k_scatter<<<(cnt + 255) / 256, 256, 0, stream>>>(I, O, M, flag, R, n, n, k0, cnt);
            conv_dispatch(cin, rows, xbf, (k0 == 0) ? 0 : 1, dim3(gridn, 1), blk,
                          X, W, bias, R, out, n, cout, k0, g, g, stream);
        }
    }
}

// ======================= BN =======================
__global__ void __launch_bounds__(256) k_stats(const float* __restrict__ X,
                                               float* __restrict__ sums, int n, int C) {
    int c = threadIdx.x, ty = threadIdx.y, ny = blockDim.y;
    float s1 = 0.f, s2 = 0.f;
    for (int o = blockIdx.x * ny + ty; o < n; o += gridDim.x * ny) {
        float v = X[(long)o * C + c];
        s1 += v;
        s2 += v * v;
    }
    __shared__ float sm[512];
    sm[ty * C + c] = s1;
    sm[256 + ty * C + c] = s2;
    __syncthreads();
    if (ty == 0) {
        for (int t = 1; t < ny; ++t) {
            s1 += sm[t * C + c];
            s2 += sm[256 + t * C + c];
        }
        atomicAdd(&sums[c], s1);
        atomicAdd(&sums[C + c], s2);
    }
}

__global__ void __launch_bounds__(256) k_apply(const float* __restrict__ X,
                                               const float* __restrict__ sums,
                                               const float* __restrict__ g,
                                               const float* __restrict__ b,
                                               void* __restrict__ Y, int ybf,
                                               unsigned short* __restrict__ Y2,
                                               long total, int maskC, int C, float inv_n) {
    long i = (long)blockIdx.x * 256 + threadIdx.x;
    if (i >= total) return;
    int c = (int)(i & (long)maskC);
    float mean = sums[c] * inv_n;
    float var = fmaf(-mean, mean, sums[C + c] * inv_n);
    float sc = g[c] * rsqrtf(var + 1e-5f);
    float sh = fmaf(-mean, sc, b[c]);
    float v = fmaf(X[i], sc, sh);
    v = v > 0.f ? v : 0.f;
    if (ybf) ((unsigned short*)Y)[i] = f2bu(v);
    else     ((float*)Y)[i] = v;
    if (Y2) Y2[i] = f2bu(v);
}

static void run_bn(const float* src, int n, int C, const float* g, const float* b,
                   void* dst, int dst_bf16, unsigned short* dst2,
                   float* sums, hipStream_t stream) {
    hipMemsetAsync(sums, 0, 2 * C * sizeof(float), stream);
    dim3 sblk(C, 256 / C);
    int sgrd = (n + (int)sblk.y - 1) / (int)sblk.y;
    if (sgrd > 1024) sgrd = 1024;
    k_stats<<<sgrd, sblk, 0, stream>>>(src, sums, n, C);
    long tot = (long)n * C;
    k_apply<<<(int)((tot + 255) / 256), 256, 0, stream>>>(src, sums, g, b, dst, dst_bf16,
                                                          dst2, tot, C - 1, C,
                                                          1.0f / (float)n);
}

extern "C" void kernel_launch(void* const* d_in, const int* in_sizes, int n_in,
                              void* d_out, int out_size, void* d_ws, size_t ws_size,
                              hipStream_t stream) {
    float* out = (float*)d_out;

    int stride = 0;
    if (n_in == 57) stride = 14;
    else if (n_in == 53) stride = 13;
    if (!stride) {
        k_sentinel<<<1, 64, 0, stream>>>(out, 10240.f + (float)n_in);
        return;
    }
    static const int o14[13] = {0, 1, 2, 3, 4, 5, 7, 8, 9, 10, 11, 12, 13};
    static const int o13[13] = {0, 1, 2, 3, 4, 5, 6, 7, 8, 9, 10, 11, 12};
    const int* om = (stride == 14) ? o14 : o13;

    long n0 = (long)in_sizes[0];
    int P[4];
    bool ok = (n0 % 16 == 0);
    long total = n0;
    for (int l = 0; l < 4 && ok; ++l) {
        int base = 1 + stride * l;
        int sdI = in_sizes[base + om[1]], sdO = in_sizes[base + om[2]], sdM = in_sizes[base + om[3]];
        int sbI = in_sizes[base + om[8]], sbO = in_sizes[base + om[9]], sbM = in_sizes[base + om[10]];
        if (sdI <= 0 || sdI % 8 != 0 || sdO != sdI || sdM != sdI) { ok = false; break; }
        int p = sdI / 8;
        if (sbI != 27 * p || sbO != sbI || sbM != sbI) { ok = false; break; }
        if (in_sizes[base + om[0]] != 8 * CH[l] * CH[l + 1]) { ok = false; break; }
        if (in_sizes[base + om[6]] != 27 * CH[l + 1] * CH[l + 1]) { ok = false; break; }
        P[l] = p;
        total += (long)p * CH[l + 1];
    }
    if (!ok) {
        k_sentinel<<<1, 64, 0, stream>>>(out, 49152.f);
        return;
    }
    if (total != (long)out_size) {
        k_sentinel<<<1, 64, 0, stream>>>(out, 53248.f);
        return;
    }

    auto al = [](size_t x) { return (x + 255) / 256 * 256; };
    size_t maxBuf = 0, maxP = 0, maxXb = 0;
    long rowsIn[4] = {n0 / 16, P[0], P[1], P[2]};
    for (int l = 0; l < 4; ++l) {
        size_t b = (size_t)P[l] * CH[l + 1];
        if (b > maxBuf) maxBuf = b;
        if ((size_t)P[l] > maxP) maxP = (size_t)P[l];
        size_t xi = (size_t)rowsIn[l] * CH[l];
        if (xi > maxXb) maxXb = xi;
    }
    const size_t fixed = 4096;
    size_t rmin = al((maxP + 16) * 4);
    size_t dwt_sz = al((size_t)8 * 128 * 256 * 2);
    size_t bwt_sz = al((size_t)27 * 256 * 256 * 2);
    size_t xb_sz = al(maxXb * 2 + 1024);
    size_t bufB_sz = al(maxBuf * 2 + 1024);
    size_t mf_need = dwt_sz + bwt_sz + xb_sz + bufB_sz + fixed + rmin;

    if (ws_size >= mf_need) {
        // ---------------- MFMA bf16 path ----------------
        char* wsp = (char*)d_ws;
        unsigned short* dWt = (unsigned short*)wsp; wsp += dwt_sz;
        unsigned short* bWt = (unsigned short*)wsp; wsp += bwt_sz;
        unsigned short* xb = (unsigned short*)wsp;  wsp += xb_sz;
        unsigned short* bufB = (unsigned short*)wsp; wsp += bufB_sz;
        // sums = 2048B (512 floats): covers cout=256 at level 3 (r9/r10 fix —
        // 1024B overflowed into flag[] and corrupted the L3 mask interpretation).
        float* sums = (float*)wsp; wsp += 2048;
        int* flag = (int*)wsp;     wsp += 2048;
        int* R = (int*)wsp;
        size_t Rbytes = ws_size - (size_t)(wsp - (char*)d_ws);

        SparseConvEncoder_20633022890309_kernel<<<1, 64, 0, stream>>>(
            (const unsigned char*)d_in[1 + om[10]], flag);
        k_copytob<<<(int)((n0 + 255) / 256), 256, 0, stream>>>((const float*)d_in[0],
                                                               out, xb, n0);

        long coff = n0;
        for (int l = 0; l < 4; ++l) {
            int base = 1 + stride * l;
            const float* dW = (const float*)d_in[base + om[0]];
            const int* dI = (const int*)d_in[base + om[1]];
            const int* dO = (const int*)d_in[base + om[2]];
            const void* dM = d_in[base + om[3]];
            const float* dG = (const float*)d_in[base + om[4]];
            const float* dB = (const float*)d_in[base + om[5]];
            const float* bW = (const float*)d_in[base + om[6]];
            const float* bC = (const float*)d_in[base + om[7]];
            const int* bI = (const int*)d_in[base + om[8]];
            const int* bO = (const int*)d_in[base + om[9]];
            const void* bM = d_in[base + om[10]];
            const float* bG = (const float*)d_in[base + om[11]];
            const float* bH = (const float*)d_in[base + om[12]];
            int n = P[l], cin = CH[l], cout = CH[l + 1];
            int nin = (int)rowsIn[l];
            int n16 = (n + 15) / 16 * 16;

            int G = (int)(Rbytes / ((size_t)n16 * 4));
            if (G > 27) G = 27;
            if (G < 1) G = 1;

            float* chunkp = out + coff;

            long dwtot = (long)8 * cin * cout;
            long bwtot = (long)27 * cout * cout;
            k_wt2<<<(int)((dwtot + bwtot + 255) / 256), 256, 0, stream>>>(
                dW, dWt, cin, bW, bWt, cout, cout, dwtot, bwtot);

            run_mconv(xb, nin, dWt, nullptr, dI, dO, dM, flag, R, chunkp,
                      n, cin, cout, 8, (G > 8) ? 8 : G, stream);
            run_bn(chunkp, n, cout, dG, dB, bufB, /*ybf=*/1, nullptr, sums, stream);

            run_mconv(bufB, n, bWt, bC, bI, bO, bM, flag, R, chunkp,
                      n, cout, cout, 27, G, stream);
            run_bn(chunkp, n, cout, bG, bH, chunkp, /*ybf=*/0,
                   (l < 3) ? xb : nullptr, sums, stream);

            coff += (long)n * cout;
        }
        return;
    }

    // ---------------- fallback VALU path ----------------
    int bufB_bf16;
    size_t bufBytes;
    if (ws_size >= fixed + al(maxBuf * 4) + rmin) { bufB_bf16 = 0; bufBytes = al(maxBuf * 4); }
    else if (ws_size >= fixed + al(maxBuf * 2) + rmin) { bufB_bf16 = 1; bufBytes = al(maxBuf * 2); }
    else {
        k_sentinel<<<1, 64, 0, stream>>>(out, 16384.f + (float)(ws_size >> 20));
        return;
    }
    size_t Rbytes = ws_size - fixed - bufBytes;
    char* wsp = (char*)d_ws;
    void* bufB = (void*)wsp;   wsp += bufBytes;
    float* sums = (float*)wsp; wsp += 2048;   // 512 floats (cout=256)
    int* flag = (int*)wsp;     wsp += 2048;
    int* R = (int*)wsp;

    SparseConvEncoder_20633022890309_kernel<<<1, 64, 0, stream>>>(
        (const unsigned char*)d_in[1 + om[10]], flag);
    k_copy<<<(int)((n0 + 255) / 256), 256, 0, stream>>>((const float*)d_in[0], out, n0);

    long coff = n0;
    const void* cur_in = d_in[0];
    int cur_xbf = 0;
    for (int l = 0; l < 4; ++l) {
        int base = 1 + stride * l;
        const float* dW = (const float*)d_in[base + om[0]];
        const int* dI = (const int*)d_in[base + om[1]];
        const int* dO = (const int*)d_in[base + om[2]];
        const void* dM = d_in[base + om[3]];
        const float* dG = (const float*)d_in[base + om[4]];
        const float* dB = (const float*)d_in[base + om[5]];
        const float* bW = (const float*)d_in[base + om[6]];
        const float* bC = (const float*)d_in[base + om[7]];
        const int* bI = (const int*)d_in[base + om[8]];
        const int* bO = (const int*)d_in[base + om[9]];
        const void* bM = d_in[base + om[10]];
        const float* bG = (const float*)d_in[base + om[11]];
        const float* bH = (const float*)d_in[base + om[12]];
        int n = P[l], cin = CH[l], cout = CH[l + 1];

        int G = (int)(Rbytes / ((size_t)n * 4));
        if (G > 27) G = 27;
        if (G < 1) G = 1;

        float* chunkp = out + coff;
        run_conv(cur_in, cur_xbf, dW, nullptr, dI, dO, dM, flag, R, chunkp,
                 n, cin, cout, 8, (G > 8) ? 8 : G, stream);
        run_bn(chunkp, n, cout, dG, dB, bufB, bufB_bf16, nullptr, sums, stream);
        run_conv(bufB, bufB_bf16, bW, bC, bI, bO, bM, flag, R, chunkp,
                 n, cout, cout, 27, G, stream);
        run_bn(chunkp, n, cout, bG, bH, chunkp, /*ybf=*/0, nullptr, sums, stream);

        cur_in = (const void*)chunkp;
        cur_xbf = 0;
        coff += (long)n * cout;
    }
}